// Round 1
// baseline (388.599 us; speedup 1.0000x reference)
//
#include <hip/hip_runtime.h>
#include <stdint.h>
#include <stddef.h>

// Causal GQA prefill attention, MI355X gfx950.
// B=2, S=2048, Hq=32, Hkv=8 (G=4), D=128, fp32 in/out, bf16 MFMA internally.
//
// Orientation trick: compute S^T = K_tile * Q_tile^T with mfma_16x16x32_bf16.
// Then S^T's C-layout (row=key=quad*4+reg, col=q=lane&15) is EXACTLY the
// A-operand layout of mfma_16x16x16bf16_1k (m=lane&15, k=quad*4+j), so the
// softmaxed P feeds the PV matmul straight from registers (no transpose).

#define S_LEN   2048
#define HQ      32
#define HKV     8
#define DH      128
#define QSTRIDE (HQ*DH)    // 4096 floats per token row of Q/O
#define KSTRIDE (HKV*DH)   // 1024 floats per token row of K/V
#define SCALE_F 0.08838834764831845f

typedef __bf16 bf16;
typedef short        s16x4 __attribute__((ext_vector_type(4)));
typedef short        s16x8 __attribute__((ext_vector_type(8)));
typedef float        f32x4 __attribute__((ext_vector_type(4)));
typedef unsigned int u32x2 __attribute__((ext_vector_type(2)));
typedef unsigned int u32x4 __attribute__((ext_vector_type(4)));

// LDS layout (per buffer): K tile 32 x 136 bf16 (128 + 8 pad), then
// V^T tile 128 x 40 bf16 (32 keys + 8 pad). Both row strides are 16B
// multiples -> b128/b64 reads stay aligned; pads break power-of-2 banks.
#define KROW     136
#define VROW     40
#define KELEMS   (32*KROW)             // 4352
#define BUFELEMS (KELEMS + DH*VROW)    // 9472 bf16 = 18944 B per buffer

__device__ __forceinline__ unsigned int pk2(float a, float b) {
  union { bf16 h[2]; unsigned int u; } x;
  x.h[0] = (bf16)a; x.h[1] = (bf16)b;    // fptrunc = RNE
  return x.u;
}

__global__ __launch_bounds__(256, 2)
void attn_fwd(const float* __restrict__ qg, const float* __restrict__ kg,
              const float* __restrict__ vg, float* __restrict__ og) {
  __shared__ bf16 smem[2*BUFELEMS];      // 37,888 B, double-buffered

  const int tid  = threadIdx.x;
  const int lane = tid & 63;
  const int wave = tid >> 6;             // 4 waves/block
  const int l15  = lane & 15;
  const int quad = lane >> 4;            // 0..3
  const int qblk = blockIdx.x;           // 0..15  (128 q rows per block)
  const int h    = blockIdx.y;           // 0..31
  const int b    = blockIdx.z;           // 0..1
  const int hkv  = h >> 2;               // G = 4
  const int qw   = qblk*128 + wave*32;   // this wave's first q row

  // ---- Q fragments: B-operand layout for S^T = K * Q^T, pre-scaled ----
  // qf[nt][c] holds Q[q = qw + nt*16 + l15][d = c*32 + quad*8 + j], j=0..7
  u32x4 qf[2][4];
#pragma unroll
  for (int nt = 0; nt < 2; ++nt) {
    const float* qp = qg + (size_t)(b*S_LEN + qw + nt*16 + l15)*QSTRIDE
                         + h*DH + quad*8;
#pragma unroll
    for (int c = 0; c < 4; ++c) {
      const float4 a4 = *(const float4*)(qp + c*32);
      const float4 b4 = *(const float4*)(qp + c*32 + 4);
      u32x4 w;
      w[0] = pk2(a4.x*SCALE_F, a4.y*SCALE_F);
      w[1] = pk2(a4.z*SCALE_F, a4.w*SCALE_F);
      w[2] = pk2(b4.x*SCALE_F, b4.y*SCALE_F);
      w[3] = pk2(b4.z*SCALE_F, b4.w*SCALE_F);
      qf[nt][c] = w;
    }
  }

  // ---- staging thread roles ----
  const int kcol4 = tid & 31;   // K: float4 column, rows krow0 + 8*it
  const int krow0 = tid >> 5;   // 0..7
  const int vkp   = tid & 15;   // V: key pair 2*vkp, 2*vkp+1
  const int vdb   = tid >> 4;   // 0..15 -> d block vdb*8..+7

  float4 kx[4], vx[4];          // prefetch registers

  auto load_tile = [&](int k0) {
#pragma unroll
    for (int it = 0; it < 4; ++it) {
      const int key = k0 + krow0 + it*8;       // always < S_LEN (causal bound)
      kx[it] = *(const float4*)(kg + (size_t)(b*S_LEN + key)*KSTRIDE
                                   + hkv*DH + kcol4*4);
    }
    const float* v0p = vg + (size_t)(b*S_LEN + k0 + 2*vkp    )*KSTRIDE + hkv*DH + vdb*8;
    const float* v1p = vg + (size_t)(b*S_LEN + k0 + 2*vkp + 1)*KSTRIDE + hkv*DH + vdb*8;
    vx[0] = *(const float4*)(v0p);  vx[1] = *(const float4*)(v0p + 4);
    vx[2] = *(const float4*)(v1p);  vx[3] = *(const float4*)(v1p + 4);
  };

  auto store_tile = [&](int bi) {
    bf16* kb = smem + bi*BUFELEMS;
#pragma unroll
    for (int it = 0; it < 4; ++it) {
      u32x2 w;
      w[0] = pk2(kx[it].x, kx[it].y);
      w[1] = pk2(kx[it].z, kx[it].w);
      *(u32x2*)(kb + (krow0 + it*8)*KROW + kcol4*4) = w;
    }
    bf16* vb = kb + KELEMS;
    const float f0[8] = {vx[0].x,vx[0].y,vx[0].z,vx[0].w,
                         vx[1].x,vx[1].y,vx[1].z,vx[1].w};
    const float f1[8] = {vx[2].x,vx[2].y,vx[2].z,vx[2].w,
                         vx[3].x,vx[3].y,vx[3].z,vx[3].w};
#pragma unroll
    for (int i = 0; i < 8; ++i)   // Vt[d][key]: pack keys (2vkp, 2vkp+1)
      *(unsigned int*)(vb + (vdb*8 + i)*VROW + 2*vkp) = pk2(f0[i], f1[i]);
  };

  // ---- accumulators ----
  f32x4 oacc[2][8];               // [q M-tile][d N-tile], C-layout
#pragma unroll
  for (int mt = 0; mt < 2; ++mt)
#pragma unroll
    for (int nd = 0; nd < 8; ++nd)
      oacc[mt][nd] = (f32x4){0.f, 0.f, 0.f, 0.f};
  float m_run[2] = {-3e38f, -3e38f};
  float l_run[2] = {0.f, 0.f};

  const int nsteps = (qblk + 1)*4;   // KV tiles of 32 keys
  load_tile(0);

  for (int i = 0; i < nsteps; ++i) {
    const int k0 = i*32;
    store_tile(i & 1);
    __syncthreads();                       // staged tile visible to all waves
    if (i + 1 < nsteps) load_tile(k0 + 32);  // prefetch overlaps compute
    if (k0 <= qw) {                        // wave-uniform causal skip
      const bf16* kb = smem + (i & 1)*BUFELEMS;
      const bf16* vb = kb + KELEMS;

      // ---- S^T = K_tile * Q^T : rows = keys (2 tiles), cols = q (2 tiles)
      f32x4 sacc[2][2];
#pragma unroll
      for (int mt = 0; mt < 2; ++mt)
#pragma unroll
        for (int nt = 0; nt < 2; ++nt)
          sacc[mt][nt] = (f32x4){0.f, 0.f, 0.f, 0.f};
#pragma unroll
      for (int c = 0; c < 4; ++c) {
        const u32x4 af0 = *(const u32x4*)(kb + l15*KROW        + c*32 + quad*8);
        const u32x4 af1 = *(const u32x4*)(kb + (16 + l15)*KROW + c*32 + quad*8);
        sacc[0][0] = __builtin_amdgcn_mfma_f32_16x16x32_bf16(
            __builtin_bit_cast(s16x8, af0), __builtin_bit_cast(s16x8, qf[0][c]),
            sacc[0][0], 0, 0, 0);
        sacc[0][1] = __builtin_amdgcn_mfma_f32_16x16x32_bf16(
            __builtin_bit_cast(s16x8, af0), __builtin_bit_cast(s16x8, qf[1][c]),
            sacc[0][1], 0, 0, 0);
        sacc[1][0] = __builtin_amdgcn_mfma_f32_16x16x32_bf16(
            __builtin_bit_cast(s16x8, af1), __builtin_bit_cast(s16x8, qf[0][c]),
            sacc[1][0], 0, 0, 0);
        sacc[1][1] = __builtin_amdgcn_mfma_f32_16x16x32_bf16(
            __builtin_bit_cast(s16x8, af1), __builtin_bit_cast(s16x8, qf[1][c]),
            sacc[1][1], 0, 0, 0);
      }

      // ---- causal mask + online softmax (per-lane state: q = nt*16 + l15)
      float p[2][2][4];
      float alpha[2];
#pragma unroll
      for (int nt = 0; nt < 2; ++nt) {
        const int qgl = qw + nt*16 + l15;
        float tmax = -3e38f;
#pragma unroll
        for (int mt = 0; mt < 2; ++mt)
#pragma unroll
          for (int r = 0; r < 4; ++r) {
            const int key = k0 + mt*16 + quad*4 + r;
            const float sv = (key <= qgl) ? sacc[mt][nt][r] : -3e38f;
            p[mt][nt][r] = sv;
            tmax = fmaxf(tmax, sv);
          }
        tmax = fmaxf(tmax, __shfl_xor(tmax, 16));
        tmax = fmaxf(tmax, __shfl_xor(tmax, 32));
        const float mnew = fmaxf(m_run[nt], tmax);
        alpha[nt] = __expf(m_run[nt] - mnew);
        float rsum = 0.f;
#pragma unroll
        for (int mt = 0; mt < 2; ++mt)
#pragma unroll
          for (int r = 0; r < 4; ++r) {
            const float e = __expf(p[mt][nt][r] - mnew);
            p[mt][nt][r] = e;
            rsum += e;
          }
        rsum += __shfl_xor(rsum, 16);
        rsum += __shfl_xor(rsum, 32);
        l_run[nt] = l_run[nt]*alpha[nt] + rsum;
        m_run[nt] = mnew;
      }

      // ---- rescale O by alpha of its own rows (rows = quad*4 + r) ----
#pragma unroll
      for (int MT = 0; MT < 2; ++MT)
#pragma unroll
        for (int r = 0; r < 4; ++r) {
          const float a = __shfl(alpha[MT], (lane & 48) | (quad*4 + r));
#pragma unroll
          for (int nd = 0; nd < 8; ++nd) oacc[MT][nd][r] *= a;
        }

      // ---- pack P to bf16 A-frags (already in A-layout for K=16 MFMA) ----
      s16x4 pa[2][2];
#pragma unroll
      for (int mt = 0; mt < 2; ++mt)
#pragma unroll
        for (int nt = 0; nt < 2; ++nt) {
          union { bf16 h[4]; s16x4 s; } u;
#pragma unroll
          for (int r = 0; r < 4; ++r) u.h[r] = (bf16)p[mt][nt][r];
          pa[mt][nt] = u.s;
        }

      // ---- O += P * V  (mfma_16x16x16bf16_1k, K-chunk = 16 keys) ----
#pragma unroll
      for (int mt = 0; mt < 2; ++mt)       // key chunk mt*16..+15
#pragma unroll
        for (int nd = 0; nd < 8; ++nd) {
          const s16x4 bv = *(const s16x4*)(vb + (nd*16 + l15)*VROW
                                              + mt*16 + quad*4);
          oacc[0][nd] = __builtin_amdgcn_mfma_f32_16x16x16bf16_1k(
              pa[mt][0], bv, oacc[0][nd], 0, 0, 0);
          oacc[1][nd] = __builtin_amdgcn_mfma_f32_16x16x16bf16_1k(
              pa[mt][1], bv, oacc[1][nd], 0, 0, 0);
        }
    }
  }

  // ---- epilogue: O / l, fp32 store ----
#pragma unroll
  for (int MT = 0; MT < 2; ++MT)
#pragma unroll
    for (int r = 0; r < 4; ++r) {
      const float li  = __shfl(l_run[MT], (lane & 48) | (quad*4 + r));
      const float inv = 1.0f / li;
      const size_t base = (size_t)(b*S_LEN + qw + MT*16 + quad*4 + r)*QSTRIDE
                        + h*DH + l15;
#pragma unroll
      for (int nd = 0; nd < 8; ++nd)
        og[base + nd*16] = oacc[MT][nd][r] * inv;
    }
}

extern "C" void kernel_launch(void* const* d_in, const int* in_sizes, int n_in,
                              void* d_out, int out_size, void* d_ws, size_t ws_size,
                              hipStream_t stream) {
  const float* q = (const float*)d_in[0];
  const float* k = (const float*)d_in[1];
  const float* v = (const float*)d_in[2];
  float* out = (float*)d_out;
  // seq_len (d_in[3]) is a compile-time constant 2048 for this problem.
  dim3 grid(S_LEN/128, HQ, 2);   // 16 x 32 x 2 = 1024 blocks
  dim3 block(256);
  attn_fwd<<<grid, block, 0, stream>>>(q, k, v, out);
}